// Round 3
// baseline (239.101 us; speedup 1.0000x reference)
//
#include <hip/hip_runtime.h>
#include <stdint.h>

#define NB 4
#define NN 1024
#define ND 64

// Static device scratch: f64 h_src / h_dst+b1
__device__ double g_hs[NB * NN * ND];
__device__ double g_hd[NB * NN * ND];

// ---- Threefry-2x32-20 core, generic key ----
__device__ __forceinline__ void threefry_core(uint32_t K0, uint32_t K1,
                                              uint32_t x0, uint32_t x1,
                                              uint32_t& o0, uint32_t& o1) {
  const uint32_t K2 = K0 ^ K1 ^ 0x1BD11BDAu;
  x0 += K0; x1 += K1;
#define TF_RND(r) { x0 += x1; x1 = (x1 << r) | (x1 >> (32 - r)); x1 ^= x0; }
  TF_RND(13) TF_RND(15) TF_RND(26) TF_RND(6)
  x0 += K1; x1 += K2 + 1u;
  TF_RND(17) TF_RND(29) TF_RND(16) TF_RND(24)
  x0 += K2; x1 += K0 + 2u;
  TF_RND(13) TF_RND(15) TF_RND(26) TF_RND(6)
  x0 += K0; x1 += K1 + 3u;
  TF_RND(17) TF_RND(29) TF_RND(16) TF_RND(24)
  x0 += K1; x1 += K2 + 4u;
  TF_RND(13) TF_RND(15) TF_RND(26) TF_RND(6)
  x0 += K2; x1 += K0 + 5u;
#undef TF_RND
  o0 = x0; o1 = x1;
}

// jax_threefry_partitionable=True (default in modern JAX) stream:
// count = uint64 flat index L -> (hi32, lo32) = (0, L) for L < 2^32;
// threefry2x32(key, hi, lo) -> (o0, o1); 32-bit word = o0 ^ o1.
__device__ __forceinline__ uint32_t rand_word(uint32_t L) {
  uint32_t o0, o1;
  threefry_core(0u, 42u, 0u, L, o0, o1);   // key = (0, 42) from jax.random.key(42)
  return o0 ^ o1;
}

// jax uniform(minval=tiny,maxval=1): u exact f32; logs in f64.
__device__ __forceinline__ double gumbel_from_word(uint32_t w) {
  uint32_t fb = (w >> 9) | 0x3f800000u;
  float f = __uint_as_float(fb) - 1.0f;          // [0,1), exact
  const float tinyf = 1.17549435e-38f;
  float u = fmaxf(tinyf, f + tinyf);             // == max(tiny, f)
  double lu = log((double)u);                    // < 0
  return -log(-lu);
}

// ---- Stage 1: h_src = nf @ W1[:D], h_dst = nf @ W1[D:] + b1  (f64 accum) ----
__global__ __launch_bounds__(256) void stage1(const float* __restrict__ nf,
                                              const float* __restrict__ W1,
                                              const float* __restrict__ b1) {
  const int tid = threadIdx.x;
  const int r = tid >> 6;            // 0..3 row within block
  const int e = tid & 63;            // output feature
  const int bn = blockIdx.x * 4 + r; // (b*N+n) flat row, 0..4095
  __shared__ float rows[4][ND];
  rows[r][e] = nf[bn * ND + e];
  __syncthreads();
  double accs = 0.0, accd = 0.0;
  #pragma unroll
  for (int k = 0; k < ND; ++k) {
    double x = (double)rows[r][k];
    accs += x * (double)W1[k * ND + e];
    accd += x * (double)W1[(ND + k) * ND + e];
  }
  g_hs[bn * ND + e] = accs;
  g_hd[bn * ND + e] = accd + (double)b1[e];
}

// ---- Stage 2: pair-tiled relu-dot, symmetrize, gumbel argmax, write ----
__global__ __launch_bounds__(256) void stage2(const float* __restrict__ W2,
                                              const float* __restrict__ b2,
                                              float* __restrict__ adj,
                                              float* __restrict__ logits) {
  const int bi = blockIdx.x, bj = blockIdx.y, b = blockIdx.z;
  if (bj < bi) return;               // pair tiles bi <= bj only

  __shared__ double hsi[16][ND + 1], hdi[16][ND + 1];
  __shared__ double hsj[16][ND + 1], hdj[16][ND + 1];
  __shared__ double w2s[ND];

  const int tid = threadIdx.x;
  const int i0 = bi * 16, j0 = bj * 16;

  for (int t = tid; t < 16 * ND; t += 256) {
    int r = t >> 6, c = t & 63;
    hsi[r][c] = g_hs[(b * NN + i0 + r) * ND + c];
    hdi[r][c] = g_hd[(b * NN + i0 + r) * ND + c];
    hsj[r][c] = g_hs[(b * NN + j0 + r) * ND + c];
    hdj[r][c] = g_hd[(b * NN + j0 + r) * ND + c];
  }
  if (tid < ND) w2s[tid] = (double)W2[tid];
  __syncthreads();

  const int tx = tid & 15, ty = tid >> 4;
  const int i = i0 + ty, j = j0 + tx;

  double l1 = 0.0, l2 = 0.0;
  #pragma unroll
  for (int d = 0; d < ND; ++d) {
    double w = w2s[d];
    double a = hsi[ty][d] + hdj[tx][d];   // logit(i,j) term
    double c = hsj[tx][d] + hdi[ty][d];   // logit(j,i) term
    l1 += (a > 0.0 ? a : 0.0) * w;
    l2 += (c > 0.0 ? c : 0.0) * w;
  }
  const double sym = 0.5 * (l1 + l2) + (double)b2[0];
  const float symf = (float)sym;

  // element (b,i,j)
  uint32_t m1 = ((uint32_t)(b * NN + i)) * NN + (uint32_t)j;
  uint32_t m2 = ((uint32_t)(b * NN + j)) * NN + (uint32_t)i;

  double g0a = gumbel_from_word(rand_word(2u * m1));
  double g1a = gumbel_from_word(rand_word(2u * m1 + 1u));
  double g0b = gumbel_from_word(rand_word(2u * m2));
  double g1b = gumbel_from_word(rand_word(2u * m2 + 1u));

  float adj1 = (i == j) ? 0.0f : ((sym + g0a >= g1a) ? 1.0f : 0.0f);
  float adj2 = (i == j) ? 0.0f : ((sym + g0b >= g1b) ? 1.0f : 0.0f);

  logits[m1] = symf;
  logits[m2] = symf;
  adj[m1] = adj1;
  adj[m2] = adj2;

  // ---- Threefry core KAT (Random123 vectors). On failure, overwrite the
  // diagonal cell adj[0,0,0] (ref = 0) with a sentinel >= 2 so the reported
  // absmax discriminates "core bug" from "wrong stream mapping" (1.0). ----
  if (bi == 0 && bj == 0 && b == 0 && tid == 0) {
    uint32_t a0, a1;
    float code = 2.0f; bool bad = false;
    threefry_core(0u, 0u, 0u, 0u, a0, a1);
    if (a0 != 0x6b200159u || a1 != 0x99ba4efeu) { bad = true; code += 0.5f; }
    threefry_core(0xFFFFFFFFu, 0xFFFFFFFFu, 0xFFFFFFFFu, 0xFFFFFFFFu, a0, a1);
    if (a0 != 0x1cb996fcu || a1 != 0xbb002be7u) { bad = true; code += 1.0f; }
    threefry_core(0x13198a2eu, 0x03707344u, 0x243f6a88u, 0x85a308d3u, a0, a1);
    if (a0 != 0xc4923a9cu || a1 != 0x483df7a0u) { bad = true; code += 2.0f; }
    if (bad) adj[0] = code;
  }
}

extern "C" void kernel_launch(void* const* d_in, const int* in_sizes, int n_in,
                              void* d_out, int out_size, void* d_ws, size_t ws_size,
                              hipStream_t stream) {
  const float* nf = (const float*)d_in[0];   // [4,1024,64]
  const float* W1 = (const float*)d_in[1];   // [128,64]
  const float* b1 = (const float*)d_in[2];   // [64]
  const float* W2 = (const float*)d_in[3];   // [64,1]
  const float* b2 = (const float*)d_in[4];   // [1]

  float* adj    = (float*)d_out;                       // [4,1024,1024]
  float* logits = adj + (size_t)NB * NN * NN;          // [4,1024,1024]

  stage1<<<dim3(NB * NN / 4), dim3(256), 0, stream>>>(nf, W1, b1);
  stage2<<<dim3(NN / 16, NN / 16, NB), dim3(256), 0, stream>>>(W2, b2, adj, logits);
}

// Round 4
// 160.772 us; speedup vs baseline: 1.4872x; 1.4872x over previous
//
#include <hip/hip_runtime.h>
#include <stdint.h>
#include <math.h>

#define NB 4
#define NN 1024
#define ND 64
#define RP 65   // padded LDS row length (f64) -> conflict-free j-side reads

// Static device scratch: f64 h_src / h_dst+b1, f64 W2
__device__ double g_hs[NB * NN * ND];
__device__ double g_hd[NB * NN * ND];
__device__ double g_w2d[ND];

// ---- Threefry-2x32-20 core, key = (0,42) ----
__device__ __forceinline__ void threefry_core(uint32_t K0, uint32_t K1,
                                              uint32_t x0, uint32_t x1,
                                              uint32_t& o0, uint32_t& o1) {
  const uint32_t K2 = K0 ^ K1 ^ 0x1BD11BDAu;
  x0 += K0; x1 += K1;
#define TF_RND(r) { x0 += x1; x1 = (x1 << r) | (x1 >> (32 - r)); x1 ^= x0; }
  TF_RND(13) TF_RND(15) TF_RND(26) TF_RND(6)
  x0 += K1; x1 += K2 + 1u;
  TF_RND(17) TF_RND(29) TF_RND(16) TF_RND(24)
  x0 += K2; x1 += K0 + 2u;
  TF_RND(13) TF_RND(15) TF_RND(26) TF_RND(6)
  x0 += K0; x1 += K1 + 3u;
  TF_RND(17) TF_RND(29) TF_RND(16) TF_RND(24)
  x0 += K1; x1 += K2 + 4u;
  TF_RND(13) TF_RND(15) TF_RND(26) TF_RND(6)
  x0 += K2; x1 += K0 + 5u;
#undef TF_RND
  o0 = x0; o1 = x1;
}

// jax_threefry_partitionable stream (verified round 3): word(L) = o0^o1 of
// threefry(key=(0,42), (0, L)).
__device__ __forceinline__ uint32_t rand_word(uint32_t L) {
  uint32_t o0, o1;
  threefry_core(0u, 42u, 0u, L, o0, o1);
  return o0 ^ o1;
}

// L = -log(u(word)); u path bit-identical to the round-3 passing kernel.
__device__ __forceinline__ double neglog_u(uint32_t idx) {
  uint32_t w = rand_word(idx);
  uint32_t fb = (w >> 9) | 0x3f800000u;
  float f = __uint_as_float(fb) - 1.0f;          // [0,1), exact
  const float tinyf = 1.17549435e-38f;
  float u = fmaxf(tinyf, f + tinyf);             // == jax uniform(tiny,1)
  return -log((double)u);                        // in (5.9e-8, 87.4)
}

// ---- Stage 1: h_src = nf @ W1[:D], h_dst = nf @ W1[D:] + b1 (f64), + W2->f64 ----
__global__ __launch_bounds__(256) void stage1(const float* __restrict__ nf,
                                              const float* __restrict__ W1,
                                              const float* __restrict__ b1,
                                              const float* __restrict__ W2) {
  __shared__ float w1s[2 * ND][ND];   // 32 KB
  __shared__ float rows[4][ND];
  const int tid = threadIdx.x;
  const float4* W14 = (const float4*)W1;
  float4* w1s4 = (float4*)w1s;
  #pragma unroll
  for (int p = 0; p < 8; ++p) w1s4[tid + 256 * p] = W14[tid + 256 * p];
  const int r = tid >> 6, e = tid & 63;
  const int bn = blockIdx.x * 4 + r;
  rows[r][e] = nf[bn * ND + e];
  __syncthreads();
  double accs = 0.0, accd = 0.0;
  #pragma unroll
  for (int k = 0; k < ND; ++k) {
    double x = (double)rows[r][k];
    accs = fma(x, (double)w1s[k][e], accs);
    accd = fma(x, (double)w1s[ND + k][e], accd);
  }
  g_hs[bn * ND + e] = accs;
  g_hd[bn * ND + e] = accd + (double)b1[e];
  if (blockIdx.x == 0 && tid < ND) g_w2d[tid] = (double)W2[tid];
}

// ---- Stage 2: 32x32 pair tile, 2x2 per thread, exp-form gumbel argmax ----
__global__ __launch_bounds__(256, 2) void stage2(const float* __restrict__ b2,
                                                 float* __restrict__ adj,
                                                 float* __restrict__ logits) {
  // triangular decode: 528 tile-pairs per batch
  const int t = blockIdx.x;
  const int b = t / 528;
  const int k = t - b * 528;
#define TRI_S(x) ((x) * 32 - ((x) * ((x) - 1)) / 2)
  int bi = (int)((65.0 - sqrt((double)(4225 - 8 * k))) * 0.5);
  while (k >= TRI_S(bi + 1)) ++bi;
  while (k < TRI_S(bi)) --bi;
  const int bj = bi + (k - TRI_S(bi));
#undef TRI_S
  const int i0 = bi * 32, j0 = bj * 32;

  __shared__ double sh_si[32][RP], sh_di[32][RP];
  __shared__ double sh_sj[32][RP], sh_dj[32][RP];
  __shared__ double w2s[ND];

  const int tid = threadIdx.x;
  {
    const int c = tid & 63, rr = tid >> 6;
    #pragma unroll
    for (int p = 0; p < 8; ++p) {
      const int r = p * 4 + rr;
      const int gi = (b * NN + i0 + r) * ND + c;
      const int gj = (b * NN + j0 + r) * ND + c;
      sh_si[r][c] = g_hs[gi];
      sh_di[r][c] = g_hd[gi];
      sh_sj[r][c] = g_hs[gj];
      sh_dj[r][c] = g_hd[gj];
    }
    if (tid < ND) w2s[tid] = g_w2d[tid];
  }
  __syncthreads();

  const int tx = tid & 15, ty = tid >> 4;

  double a1[2][2] = {{0.0, 0.0}, {0.0, 0.0}};   // logit(i,j)
  double a2[2][2] = {{0.0, 0.0}, {0.0, 0.0}};   // logit(j,i)

  #pragma unroll 4
  for (int d = 0; d < ND; ++d) {
    const double w = w2s[d];
    double si[2], di[2], sj[2], dj[2];
    si[0] = sh_si[ty][d];      si[1] = sh_si[ty + 16][d];
    di[0] = sh_di[ty][d];      di[1] = sh_di[ty + 16][d];
    sj[0] = sh_sj[tx][d];      sj[1] = sh_sj[tx + 16][d];
    dj[0] = sh_dj[tx][d];      dj[1] = sh_dj[tx + 16][d];
    #pragma unroll
    for (int a = 0; a < 2; ++a)
      #pragma unroll
      for (int c = 0; c < 2; ++c) {
        a1[a][c] = fma(fmax(si[a] + dj[c], 0.0), w, a1[a][c]);
        a2[a][c] = fma(fmax(sj[c] + di[a], 0.0), w, a2[a][c]);
      }
  }

  const double b2d = (double)b2[0];

  #pragma unroll
  for (int a = 0; a < 2; ++a)
    #pragma unroll
    for (int c = 0; c < 2; ++c) {
      const int i = i0 + ty + 16 * a;
      const int j = j0 + tx + 16 * c;
      const double sym = 0.5 * (a1[a][c] + a2[a][c]) + b2d;
      const float symf = (float)sym;
      const double E = exp(sym);            // |sym| < 709 -> finite

      const uint32_t m1 = ((uint32_t)(b * NN + i)) * NN + (uint32_t)j;
      const uint32_t m2 = ((uint32_t)(b * NN + j)) * NN + (uint32_t)i;

      // sym + g0 >= g1  <=>  exp(sym) * L1 >= L0,  L = -log(u)
      const double L0a = neglog_u(2u * m1), L1a = neglog_u(2u * m1 + 1u);
      const double L0b = neglog_u(2u * m2), L1b = neglog_u(2u * m2 + 1u);

      const float adj1 = (i == j) ? 0.0f : ((E * L1a >= L0a) ? 1.0f : 0.0f);
      const float adj2 = (i == j) ? 0.0f : ((E * L1b >= L0b) ? 1.0f : 0.0f);

      logits[m1] = symf;
      logits[m2] = symf;
      adj[m1] = adj1;
      adj[m2] = adj2;
    }
}

extern "C" void kernel_launch(void* const* d_in, const int* in_sizes, int n_in,
                              void* d_out, int out_size, void* d_ws, size_t ws_size,
                              hipStream_t stream) {
  const float* nf = (const float*)d_in[0];   // [4,1024,64]
  const float* W1 = (const float*)d_in[1];   // [128,64]
  const float* b1 = (const float*)d_in[2];   // [64]
  const float* W2 = (const float*)d_in[3];   // [64,1]
  const float* b2 = (const float*)d_in[4];   // [1]

  float* adj    = (float*)d_out;                       // [4,1024,1024]
  float* logits = adj + (size_t)NB * NN * NN;          // [4,1024,1024]

  stage1<<<dim3(NB * NN / 4), dim3(256), 0, stream>>>(nf, W1, b1, W2);
  stage2<<<dim3(NB * 528), dim3(256), 0, stream>>>(b2, adj, logits);
}

// Round 6
// 158.837 us; speedup vs baseline: 1.5053x; 1.0122x over previous
//
#include <hip/hip_runtime.h>
#include <stdint.h>
#include <math.h>

#define NB 4
#define NN 1024
#define ND 64
#define RP 68   // padded f32 LDS row (multiple of 4 for b128 alignment)

// Static device scratch: f64 (exact fallback) + f32 (fast path) h arrays
__device__ double g_hs64[NB * NN * ND];
__device__ double g_hd64[NB * NN * ND];
__device__ float  g_hs32[NB * NN * ND];
__device__ float  g_hd32[NB * NN * ND];
__device__ double g_w2d[ND];
__device__ float  g_w2f[ND];

// ---- Threefry-2x32-20 core ----
__device__ __forceinline__ void threefry_core(uint32_t K0, uint32_t K1,
                                              uint32_t x0, uint32_t x1,
                                              uint32_t& o0, uint32_t& o1) {
  const uint32_t K2 = K0 ^ K1 ^ 0x1BD11BDAu;
  x0 += K0; x1 += K1;
#define TF_RND(r) { x0 += x1; x1 = (x1 << r) | (x1 >> (32 - r)); x1 ^= x0; }
  TF_RND(13) TF_RND(15) TF_RND(26) TF_RND(6)
  x0 += K1; x1 += K2 + 1u;
  TF_RND(17) TF_RND(29) TF_RND(16) TF_RND(24)
  x0 += K2; x1 += K0 + 2u;
  TF_RND(13) TF_RND(15) TF_RND(26) TF_RND(6)
  x0 += K0; x1 += K1 + 3u;
  TF_RND(17) TF_RND(29) TF_RND(16) TF_RND(24)
  x0 += K1; x1 += K2 + 4u;
  TF_RND(13) TF_RND(15) TF_RND(26) TF_RND(6)
  x0 += K2; x1 += K0 + 5u;
#undef TF_RND
  o0 = x0; o1 = x1;
}

// jax_threefry_partitionable stream (verified r3): word(L) = o0^o1, x=(0,L)
__device__ __forceinline__ uint32_t rand_word(uint32_t L) {
  uint32_t o0, o1;
  threefry_core(0u, 42u, 0u, L, o0, o1);
  return o0 ^ o1;
}

// exact f32 uniform(tiny,1) — bit-identical to JAX
__device__ __forceinline__ float u_from_word(uint32_t w) {
  uint32_t fb = (w >> 9) | 0x3f800000u;
  float f = __uint_as_float(fb) - 1.0f;
  const float tinyf = 1.17549435e-38f;
  return fmaxf(tinyf, f + tinyf);
}

// ---- exact-f64 fallback for near-boundary cells (matches r3/r4 pipeline) ----
__device__ __attribute__((noinline)) float decide_fallback(int b, int i, int j,
                                                           uint32_t m, double b2d) {
  const double* hsi = g_hs64 + ((size_t)(b * NN + i)) * ND;
  const double* hdi = g_hd64 + ((size_t)(b * NN + i)) * ND;
  const double* hsj = g_hs64 + ((size_t)(b * NN + j)) * ND;
  const double* hdj = g_hd64 + ((size_t)(b * NN + j)) * ND;
  double l1 = 0.0, l2 = 0.0;
  for (int d = 0; d < ND; ++d) {
    double w = g_w2d[d];
    l1 += fmax(hsi[d] + hdj[d], 0.0) * w;
    l2 += fmax(hsj[d] + hdi[d], 0.0) * w;
  }
  double sym = 0.5 * (l1 + l2) + b2d;
  double E = exp(sym);
  double L0 = -log((double)u_from_word(rand_word(2u * m)));
  double L1 = -log((double)u_from_word(rand_word(2u * m + 1u)));
  return (E * L1 >= L0) ? 1.0f : 0.0f;
}

// ---- Stage 1: f64 h arrays + f32 copies + W2 broadcast ----
__global__ __launch_bounds__(256) void stage1(const float* __restrict__ nf,
                                              const float* __restrict__ W1,
                                              const float* __restrict__ b1,
                                              const float* __restrict__ W2) {
  __shared__ float w1s[2 * ND][ND];   // 32 KB
  __shared__ float rows[4][ND];
  const int tid = threadIdx.x;
  const float4* W14 = (const float4*)W1;
  float4* w1s4 = (float4*)w1s;
  #pragma unroll
  for (int p = 0; p < 8; ++p) w1s4[tid + 256 * p] = W14[tid + 256 * p];
  const int r = tid >> 6, e = tid & 63;
  const int bn = blockIdx.x * 4 + r;
  rows[r][e] = nf[bn * ND + e];
  __syncthreads();
  double accs = 0.0, accd = 0.0;
  #pragma unroll
  for (int k = 0; k < ND; ++k) {
    double x = (double)rows[r][k];
    accs = fma(x, (double)w1s[k][e], accs);
    accd = fma(x, (double)w1s[ND + k][e], accd);
  }
  accd += (double)b1[e];
  const int o = bn * ND + e;
  g_hs64[o] = accs;  g_hd64[o] = accd;
  g_hs32[o] = (float)accs;  g_hd32[o] = (float)accd;
  if (blockIdx.x == 0 && tid < ND) {
    g_w2d[tid] = (double)W2[tid];
    g_w2f[tid] = W2[tid];
  }
}

// ---- Stage 2: f32 32x32 pair tile, 2x2/thread, f32 gumbel + f64 fallback ----
__global__ __launch_bounds__(256, 4) void stage2(const float* __restrict__ b2,
                                                 float* __restrict__ adj,
                                                 float* __restrict__ logits) {
  const int t = blockIdx.x;
  const int b = t / 528;
  const int k = t - b * 528;
#define TRI_S(x) ((x) * 32 - ((x) * ((x) - 1)) / 2)
  int bi = (int)((65.0 - sqrt((double)(4225 - 8 * k))) * 0.5);
  while (k >= TRI_S(bi + 1)) ++bi;
  while (k < TRI_S(bi)) --bi;
  const int bj = bi + (k - TRI_S(bi));
#undef TRI_S
  const int i0 = bi * 32, j0 = bj * 32;

  __shared__ float sh_si[32][RP], sh_di[32][RP];
  __shared__ float sh_sj[32][RP], sh_dj[32][RP];
  __shared__ float w2s[ND];

  const int tid = threadIdx.x;
  {
    const float4* src_si = (const float4*)(g_hs32 + ((size_t)(b * NN + i0)) * ND);
    const float4* src_di = (const float4*)(g_hd32 + ((size_t)(b * NN + i0)) * ND);
    const float4* src_sj = (const float4*)(g_hs32 + ((size_t)(b * NN + j0)) * ND);
    const float4* src_dj = (const float4*)(g_hd32 + ((size_t)(b * NN + j0)) * ND);
    #pragma unroll
    for (int p = 0; p < 2; ++p) {
      const int q = tid + 256 * p;          // float4 index, 0..511
      const int r = q >> 4, c4 = (q & 15) << 2;
      *(float4*)&sh_si[r][c4] = src_si[q];
      *(float4*)&sh_di[r][c4] = src_di[q];
      *(float4*)&sh_sj[r][c4] = src_sj[q];
      *(float4*)&sh_dj[r][c4] = src_dj[q];
    }
    if (tid < ND) w2s[tid] = g_w2f[tid];
  }
  __syncthreads();

  const int tx = tid & 15, ty = tid >> 4;

  float a1[2][2] = {{0.f, 0.f}, {0.f, 0.f}};
  float a2[2][2] = {{0.f, 0.f}, {0.f, 0.f}};

  #pragma unroll 4
  for (int d = 0; d < ND; d += 4) {
    float wv[4], si[2][4], di[2][4], sj[2][4], dj[2][4];
    *(float4*)wv    = *(const float4*)&w2s[d];
    *(float4*)si[0] = *(const float4*)&sh_si[ty][d];
    *(float4*)si[1] = *(const float4*)&sh_si[ty + 16][d];
    *(float4*)di[0] = *(const float4*)&sh_di[ty][d];
    *(float4*)di[1] = *(const float4*)&sh_di[ty + 16][d];
    *(float4*)sj[0] = *(const float4*)&sh_sj[tx][d];
    *(float4*)sj[1] = *(const float4*)&sh_sj[tx + 16][d];
    *(float4*)dj[0] = *(const float4*)&sh_dj[tx][d];
    *(float4*)dj[1] = *(const float4*)&sh_dj[tx + 16][d];
    #pragma unroll
    for (int dd = 0; dd < 4; ++dd) {
      const float w = wv[dd];
      #pragma unroll
      for (int a = 0; a < 2; ++a)
        #pragma unroll
        for (int c = 0; c < 2; ++c) {
          a1[a][c] = fmaf(fmaxf(si[a][dd] + dj[c][dd], 0.f), w, a1[a][c]);
          a2[a][c] = fmaf(fmaxf(sj[c][dd] + di[a][dd], 0.f), w, a2[a][c]);
        }
    }
  }

  const float b2f = b2[0];
  const double b2d = (double)b2f;

  #pragma unroll
  for (int a = 0; a < 2; ++a)
    #pragma unroll
    for (int c = 0; c < 2; ++c) {
      const int i = i0 + ty + 16 * a;
      const int j = j0 + tx + 16 * c;
      const float symf = 0.5f * (a1[a][c] + a2[a][c]) + b2f;
      const uint32_t m1 = (uint32_t)((b * NN + i) * NN + j);
      const uint32_t m2 = (uint32_t)((b * NN + j) * NN + i);

      const float E = __expf(symf);
      const float L0a = -__logf(u_from_word(rand_word(2u * m1)));
      const float L1a = -__logf(u_from_word(rand_word(2u * m1 + 1u)));
      const float L0b = -__logf(u_from_word(rand_word(2u * m2)));
      const float L1b = -__logf(u_from_word(rand_word(2u * m2 + 1u)));

      float adj1, adj2;
      if (i == j) {
        adj1 = 0.f; adj2 = 0.f;
      } else {
        const float pa = E * L1a, da = pa - L0a;
        const float pb = E * L1b, db = pb - L0b;
        const bool flagA = (fabsf(da) < 2e-3f * (pa + L0a)) || ((pa + L0a) < 2e-6f);
        const bool flagB = (fabsf(db) < 2e-3f * (pb + L0b)) || ((pb + L0b) < 2e-6f);
        adj1 = flagA ? decide_fallback(b, i, j, m1, b2d) : (da >= 0.f ? 1.f : 0.f);
        adj2 = flagB ? decide_fallback(b, i, j, m2, b2d) : (db >= 0.f ? 1.f : 0.f);
      }

      logits[m1] = symf;
      logits[m2] = symf;
      adj[m1] = adj1;
      adj[m2] = adj2;
    }
}

extern "C" void kernel_launch(void* const* d_in, const int* in_sizes, int n_in,
                              void* d_out, int out_size, void* d_ws, size_t ws_size,
                              hipStream_t stream) {
  const float* nf = (const float*)d_in[0];   // [4,1024,64]
  const float* W1 = (const float*)d_in[1];   // [128,64]
  const float* b1 = (const float*)d_in[2];   // [64]
  const float* W2 = (const float*)d_in[3];   // [64,1]
  const float* b2 = (const float*)d_in[4];   // [1]

  float* adj    = (float*)d_out;                       // [4,1024,1024]
  float* logits = adj + (size_t)NB * NN * NN;          // [4,1024,1024]

  stage1<<<dim3(NB * NN / 4), dim3(256), 0, stream>>>(nf, W1, b1, W2);
  stage2<<<dim3(NB * 528), dim3(256), 0, stream>>>(b2, adj, logits);
}